// Round 9
// baseline (355.699 us; speedup 1.0000x reference)
//
#include <hip/hip_runtime.h>
#include <math.h>

// Problem constants
#define BATCH   8
#define QLEN    256
#define KLEN    2048
#define KDIM    512
#define NHEADS  4
#define DKH     128
#define NG      5                       // mono + 4 heads
#define QROWS   (BATCH * QLEN)          // 2048
#define GCOLS   (NG * 512)              // 2560

static constexpr float INV_SCALE = 0.04419417382415922f; // 1/sqrt(512)
static constexpr float EPSV = 1e-6f;

typedef __attribute__((ext_vector_type(8))) short bf16x8;
typedef __attribute__((ext_vector_type(4))) float f32x4;

__device__ __forceinline__ unsigned short f2bf(float f) {
    unsigned u = __builtin_bit_cast(unsigned, f);
    u += 0x7fffu + ((u >> 16) & 1u);   // round-to-nearest-even
    return (unsigned short)(u >> 16);
}
__device__ __forceinline__ float bf2f(unsigned short u) {
    unsigned x = (unsigned)u << 16;
    return __builtin_bit_cast(float, x);
}

// Barrier waiting only on LDS ops (lgkmcnt); global loads/stores stay in flight.
__device__ __forceinline__ void lds_barrier() {
    __asm__ volatile("s_waitcnt lgkmcnt(0)\n\ts_barrier" ::: "memory");
}

// Async global->LDS, 16 B per lane (wave-uniform base + lane*16 rule).
__device__ __forceinline__ void gload_lds16(const void* g, void* l) {
    __builtin_amdgcn_global_load_lds(
        (const __attribute__((address_space(1))) void*)g,
        (__attribute__((address_space(3))) void*)l, 16, 0, 0);
}

// ---------------------------------------------------------------------------
// Staged NT MFMA core (bf16 inputs via global_load_lds): 128x128 f32 tile.
// 256 threads / 4 waves, each wave a 64x64 subtile.
// ---------------------------------------------------------------------------
__device__ __forceinline__ void mfma_nt_staged(
    const unsigned short* __restrict__ A, const unsigned short* __restrict__ B,
    int lda, int ldb, int bm, int bn,
    unsigned short* AsLDS, unsigned short* BsLDS, f32x4 acc[4][4], int ksteps)
{
    const int t = threadIdx.x;
    const int wv = t >> 6, ln = t & 63;
    const int r = ln & 15, quad = ln >> 4;
    const int wm = (wv >> 1) * 64, wn = (wv & 1) * 64;
    const int srow = wv * 16 + (ln >> 2);
    const int scol = (ln & 3) * 8;

    for (int ks = 0; ks < ksteps; ++ks) {
        const int k0 = ks * 32;
        #pragma unroll
        for (int j = 0; j < 2; ++j) {
            gload_lds16(A + (size_t)(bm + j * 64 + srow) * lda + k0 + scol,
                        AsLDS + (size_t)(j * 64 + wv * 16) * 32);
            gload_lds16(B + (size_t)(bn + j * 64 + srow) * ldb + k0 + scol,
                        BsLDS + (size_t)(j * 64 + wv * 16) * 32);
        }
        __syncthreads();
        bf16x8 af[4], bg[4];
        #pragma unroll
        for (int f = 0; f < 4; ++f)
            af[f] = *(const bf16x8*)(AsLDS + (size_t)(wm + f * 16 + r) * 32 + quad * 8);
        #pragma unroll
        for (int f = 0; f < 4; ++f)
            bg[f] = *(const bf16x8*)(BsLDS + (size_t)(wn + f * 16 + r) * 32 + quad * 8);
        #pragma unroll
        for (int i = 0; i < 4; ++i)
            #pragma unroll
            for (int j2 = 0; j2 < 4; ++j2)
                acc[i][j2] = __builtin_amdgcn_mfma_f32_16x16x32_bf16(
                    af[i], bg[j2], acc[i][j2], 0, 0, 0);
        __syncthreads();
    }
}

// Same core but A/B are f32 in HBM; staged via reg-cast (f2bf) + ds_write_b128.
// Produces bit-identical bf16 operands to the pre-cast path.
__device__ __forceinline__ void mfma_nt_staged_f32(
    const float* __restrict__ A, const float* __restrict__ B,
    int lda, int ldb, int bm, int bn,
    unsigned short* AsLDS, unsigned short* BsLDS, f32x4 acc[4][4], int ksteps)
{
    const int t = threadIdx.x;
    const int wv = t >> 6, ln = t & 63;
    const int r = ln & 15, quad = ln >> 4;
    const int wm = (wv >> 1) * 64, wn = (wv & 1) * 64;
    const int srow = wv * 16 + (ln >> 2);
    const int scol = (ln & 3) * 8;

    for (int ks = 0; ks < ksteps; ++ks) {
        const int k0 = ks * 32;
        #pragma unroll
        for (int j = 0; j < 2; ++j) {
            const float* ap = A + (size_t)(bm + j * 64 + srow) * lda + k0 + scol;
            float4 a0 = *(const float4*)ap, a1 = *(const float4*)(ap + 4);
            bf16x8 av;
            av[0] = (short)f2bf(a0.x); av[1] = (short)f2bf(a0.y);
            av[2] = (short)f2bf(a0.z); av[3] = (short)f2bf(a0.w);
            av[4] = (short)f2bf(a1.x); av[5] = (short)f2bf(a1.y);
            av[6] = (short)f2bf(a1.z); av[7] = (short)f2bf(a1.w);
            *(bf16x8*)(AsLDS + (size_t)(j * 64 + wv * 16) * 32 + ln * 8) = av;
            const float* bp = B + (size_t)(bn + j * 64 + srow) * ldb + k0 + scol;
            float4 b0 = *(const float4*)bp, b1 = *(const float4*)(bp + 4);
            bf16x8 bv;
            bv[0] = (short)f2bf(b0.x); bv[1] = (short)f2bf(b0.y);
            bv[2] = (short)f2bf(b0.z); bv[3] = (short)f2bf(b0.w);
            bv[4] = (short)f2bf(b1.x); bv[5] = (short)f2bf(b1.y);
            bv[6] = (short)f2bf(b1.z); bv[7] = (short)f2bf(b1.w);
            *(bf16x8*)(BsLDS + (size_t)(j * 64 + wv * 16) * 32 + ln * 8) = bv;
        }
        __syncthreads();
        bf16x8 af[4], bg[4];
        #pragma unroll
        for (int f = 0; f < 4; ++f)
            af[f] = *(const bf16x8*)(AsLDS + (size_t)(wm + f * 16 + r) * 32 + quad * 8);
        #pragma unroll
        for (int f = 0; f < 4; ++f)
            bg[f] = *(const bf16x8*)(BsLDS + (size_t)(wn + f * 16 + r) * 32 + quad * 8);
        #pragma unroll
        for (int i = 0; i < 4; ++i)
            #pragma unroll
            for (int j2 = 0; j2 < 4; ++j2)
                acc[i][j2] = __builtin_amdgcn_mfma_f32_16x16x32_bf16(
                    af[i], bg[j2], acc[i][j2], 0, 0, 0);
        __syncthreads();
    }
}

__device__ __forceinline__ void zero_acc(f32x4 acc[4][4]) {
    #pragma unroll
    for (int i = 0; i < 4; ++i)
        #pragma unroll
        for (int j = 0; j < 4; ++j)
            acc[i][j] = f32x4{0.f, 0.f, 0.f, 0.f};
}

// ---------------------------------------------------------------------------
// prep_g: input casts + G matrices + bias-fold vectors, ONE launch (was 2).
//  blocks [0, 8192)        cast key_enc -> kx (bf16)
//  blocks [8192, 9216)     cast query   -> qx (bf16)
//  blocks [9216, 9296)     G-matrix tiles (f32-staged MFMA; same f2bf rounding)
//  blocks [9296, 9309)     aux bias-fold vectors
// ---------------------------------------------------------------------------
#define NKXB 8192
#define NQXB 1024
__global__ __launch_bounds__(256) void prep_g(
    const float* __restrict__ key_enc, const float* __restrict__ query,
    const float* __restrict__ Wk_m, const float* __restrict__ Wk_c,
    const float* __restrict__ Wq_m, const float* __restrict__ Wq_c,
    const float* __restrict__ bq_m, const float* __restrict__ bk_m,
    const float* __restrict__ bq_c,
    unsigned short* __restrict__ kx, unsigned short* __restrict__ qx,
    unsigned short* __restrict__ GT, float* __restrict__ aux)
{
    __shared__ unsigned short As[128 * 32];
    __shared__ unsigned short Bs[128 * 32];
    __shared__ float red[256];
    const int gb = blockIdx.x, tid = threadIdx.x;

    if (gb < NKXB + NQXB) {
        const float* x = (gb < NKXB) ? key_enc : query;
        unsigned short* y = (gb < NKXB) ? kx : qx;
        const int i = (gb < NKXB ? gb : gb - NKXB) * 256 + tid;
        float4 v = ((const float4*)x)[i];
        ushort4 o;
        o.x = f2bf(v.x); o.y = f2bf(v.y); o.z = f2bf(v.z); o.w = f2bf(v.w);
        ((ushort4*)y)[i] = o;
        return;
    }
    const int t = gb - NKXB - NQXB;          // 0..92
    if (t < 80) {
        const int seg = t >> 4, tt = t & 15;
        const int bm = (tt >> 2) * 128, bn = (tt & 3) * 128;
        const float *A, *B; int ks;
        if (seg == 0) { A = Wk_m; B = Wq_m; ks = 16; }
        else { const int h = seg - 1; A = Wk_c + h * 128; B = Wq_c + h * 128; ks = 4; }
        f32x4 acc[4][4]; zero_acc(acc);
        mfma_nt_staged_f32(A, B, 512, 512, bm, bn, As, Bs, acc, ks);
        const int wv = tid >> 6, ln = tid & 63;
        const int r = ln & 15, quad = ln >> 4;
        const int m0 = bm + (wv >> 1) * 64, n0 = bn + (wv & 1) * 64;
        #pragma unroll
        for (int j = 0; j < 4; ++j) {
            const int n = n0 + j * 16 + r;
            #pragma unroll
            for (int i = 0; i < 4; ++i)
                #pragma unroll
                for (int reg = 0; reg < 4; ++reg) {
                    const int m = m0 + i * 16 + quad * 4 + reg;
                    GT[(size_t)(seg * 512 + m) * 512 + n] = f2bf(acc[i][j][reg]);
                }
        }
        return;
    }
    const int ab = t - 80;
    if (ab < 2) {                       // mono wv: Wk_m @ bq_m
        const int d = ab * 256 + tid;
        const float* row = Wk_m + (size_t)d * 512;
        float s = 0.f;
        for (int j = 0; j < 512; j += 4) {
            float4 a = *(const float4*)(row + j);
            float4 b = *(const float4*)(bq_m + j);
            s += a.x * b.x + a.y * b.y + a.z * b.z + a.w * b.w;
        }
        aux[d] = s; return;
    }
    if (ab < 10) {                      // head wv: Wk_c[:,h-slice] @ bq_c[h-slice]
        const int tt = ab - 2, h = tt >> 1;
        const int d = (tt & 1) * 256 + tid;
        const float* row = Wk_c + (size_t)d * 512 + h * 128;
        const float* bv = bq_c + h * 128;
        float s = 0.f;
        for (int j = 0; j < 128; j += 4) {
            float4 a = *(const float4*)(row + j);
            float4 b = *(const float4*)(bv + j);
            s += a.x * b.x + a.y * b.y + a.z * b.z + a.w * b.w;
        }
        aux[512 + h * 512 + d] = s; return;
    }
    if (ab < 12) {                      // wu: Wq_m @ bk_m
        const int d = (ab - 10) * 256 + tid;
        const float* row = Wq_m + (size_t)d * 512;
        float s = 0.f;
        for (int j = 0; j < 512; j += 4) {
            float4 a = *(const float4*)(row + j);
            float4 b = *(const float4*)(bk_m + j);
            s += a.x * b.x + a.y * b.y + a.z * b.z + a.w * b.w;
        }
        aux[GCOLS + d] = s; return;
    }
    // cc = dot(bq_m, bk_m)
    float s = bq_m[tid] * bk_m[tid] + bq_m[tid + 256] * bk_m[tid + 256];
    red[tid] = s; __syncthreads();
    for (int o = 128; o > 0; o >>= 1) {
        if (tid < o) red[tid] += red[tid + o];
        __syncthreads();
    }
    if (tid == 0) aux[GCOLS + 512] = red[0];
}

// ---------------------------------------------------------------------------
// qg_kernel: qg[2048][2560] bf16 = qx @ GT^T + wv  (NT, K=512).
// Blocks 0..319: 128x128 tiles. Blocks 320..327: vq2[q] = (qx[q].wu + cc)/scale.
// ---------------------------------------------------------------------------
__global__ __launch_bounds__(256) void qg_kernel(
    const unsigned short* __restrict__ qx, const unsigned short* __restrict__ GT,
    const float* __restrict__ aux,
    unsigned short* __restrict__ qg, float* __restrict__ vq2)
{
    __shared__ unsigned short As[128 * 32];
    __shared__ unsigned short Bs[128 * 32];
    __shared__ float wuS[512];
    const int v = blockIdx.x, tid = threadIdx.x;
    if (v < 320) {
        const int by = v / 20, bx = v % 20;
        const int bm = by * 128, bn = bx * 128;
        f32x4 acc[4][4]; zero_acc(acc);
        mfma_nt_staged(qx, GT, 512, 512, bm, bn, As, Bs, acc, 16);
        const int wv = tid >> 6, ln = tid & 63;
        const int r = ln & 15, quad = ln >> 4;
        const int m0 = bm + (wv >> 1) * 64, n0 = bn + (wv & 1) * 64;
        #pragma unroll
        for (int j = 0; j < 4; ++j) {
            const int n = n0 + j * 16 + r;
            const float wvb = aux[n];
            #pragma unroll
            for (int i = 0; i < 4; ++i)
                #pragma unroll
                for (int reg = 0; reg < 4; ++reg) {
                    const int m = m0 + i * 16 + quad * 4 + reg;
                    qg[(size_t)m * GCOLS + n] = f2bf(acc[i][j][reg] + wvb);
                }
        }
        return;
    }
    // vq2
    wuS[tid] = aux[GCOLS + tid];
    wuS[tid + 256] = aux[GCOLS + tid + 256];
    __syncthreads();
    const float cc = aux[GCOLS + 512];
    const int q = (v - 320) * 256 + tid;
    const unsigned short* row = qx + (size_t)q * 512;
    float s = 0.f;
    for (int j = 0; j < 512; j += 4) {
        ushort4 a = *(const ushort4*)(row + j);
        s = fmaf(bf2f(a.x), wuS[j], s);
        s = fmaf(bf2f(a.y), wuS[j + 1], s);
        s = fmaf(bf2f(a.z), wuS[j + 2], s);
        s = fmaf(bf2f(a.w), wuS[j + 3], s);
    }
    vq2[q] = (s + cc) * INV_SCALE;
}

// ---------------------------------------------------------------------------
// p_choose: p = sigmoid(qg_mono[b] @ kx[b]^T / scale + vq2 + r + noise)
// ---------------------------------------------------------------------------
__global__ __launch_bounds__(256) void pchoose_mfma(
    const unsigned short* __restrict__ qg, const unsigned short* __restrict__ kx,
    const float* __restrict__ noise, const float* __restrict__ rp,
    const float* __restrict__ vq2, float* __restrict__ p)
{
    __shared__ unsigned short As[128 * 32];
    __shared__ unsigned short Bs[128 * 32];
    const int b = blockIdx.z;
    const unsigned short* A = qg + (size_t)b * QLEN * GCOLS;      // mono cols 0..512
    const unsigned short* B = kx + (size_t)b * KLEN * 512;
    const int bm = blockIdx.y * 128, bn = blockIdx.x * 128;
    f32x4 acc[4][4]; zero_acc(acc);
    mfma_nt_staged(A, B, GCOLS, 512, bm, bn, As, Bs, acc, 16);
    const int wv = threadIdx.x >> 6, ln = threadIdx.x & 63;
    const int r = ln & 15, quad = ln >> 4;
    const int m0 = bm + (wv >> 1) * 64, n0 = bn + (wv & 1) * 64;
    const float rv = rp[0];
    #pragma unroll
    for (int i = 0; i < 4; ++i) {
        #pragma unroll
        for (int reg = 0; reg < 4; ++reg) {
            const int q = m0 + i * 16 + quad * 4 + reg;
            const size_t rowoff = ((size_t)b * QLEN + q) * KLEN;
            const float vq = vq2[b * QLEN + q] + rv;
            #pragma unroll
            for (int j = 0; j < 4; ++j) {
                const int k = n0 + j * 16 + r;
                const float e = acc[i][j][reg] * INV_SCALE + vq + noise[rowoff + k];
                p[rowoff + k] = __builtin_amdgcn_rcpf(1.0f + __expf(-e));
            }
        }
    }
}

// ---------------------------------------------------------------------------
// 64-lane inclusive prefix sum via DPP (≈6 VALU ops)
// ---------------------------------------------------------------------------
__device__ __forceinline__ float wave_incl_scan(float x)
{
#define DPP_ADD(ctrl, rmask, bctrl)                                            \
    { int _t = __builtin_amdgcn_update_dpp(0, __builtin_bit_cast(int, x),      \
                                           ctrl, rmask, 0xf, bctrl);           \
      x += __builtin_bit_cast(float, _t); }
    DPP_ADD(0x111, 0xf, true)   // row_shr:1
    DPP_ADD(0x112, 0xf, true)   // row_shr:2
    DPP_ADD(0x114, 0xf, true)   // row_shr:4
    DPP_ADD(0x118, 0xf, true)   // row_shr:8
    DPP_ADD(0x142, 0xa, false)  // row_bcast:15 -> rows 1,3
    DPP_ADD(0x143, 0xc, false)  // row_bcast:31 -> rows 2,3
#undef DPP_ADD
    return x;
}

// Inclusive prefix over lanes 0..7 (valid in those lanes only; row_shr DPP).
__device__ __forceinline__ float row_prefix8(float x)
{
#define DPP_ADD(ctrl)                                                          \
    { int _t = __builtin_amdgcn_update_dpp(0, __builtin_bit_cast(int, x),      \
                                           ctrl, 0xf, 0xf, true);              \
      x += __builtin_bit_cast(float, _t); }
    DPP_ADD(0x111)   // row_shr:1
    DPP_ADD(0x112)   // row_shr:2
    DPP_ADD(0x114)   // row_shr:4
#undef DPP_ADD
    return x;
}

// Cumprod helpers (exactly cumprod_mr's math on 4 elems/thread):
// PREP: l=log(clip(1-p)); in-lane exclusive prefix; wave scan; TP = per-lane
// exclusive partial (wave base added post-barrier). STOT = wave total.
#define CUMPREP(PV, TP, STOT)                                                  \
    {                                                                          \
        const float l0_ = __logf(fminf(fmaxf(1.0f - (PV).x, EPSV), 1.0f));     \
        const float l1_ = __logf(fminf(fmaxf(1.0f - (PV).y, EPSV), 1.0f));     \
        const float l2_ = __logf(fminf(fmaxf(1.0f - (PV).z, EPSV), 1.0f));     \
        const float l3_ = __logf(fminf(fmaxf(1.0f - (PV).w, EPSV), 1.0f));     \
        const float e1_ = l0_, e2_ = l0_ + l1_, e3_ = e2_ + l2_;               \
        const float run_ = e3_ + l3_;                                          \
        STOT = wave_incl_scan(run_);                                           \
        const float wb_ = STOT - run_;                                         \
        (TP).x = wb_; (TP).y = wb_ + e1_; (TP).z = wb_ + e2_;                  \
        (TP).w = wb_ + e3_;                                                    \
    }
// FIN: cp = exp(wex + tp); m = p*cp; r = rcp(clip(cp,EPSV,1)).
#define CUMFIN(PV, TP, WEX, M, R)                                              \
    {                                                                          \
        const float c0_ = __expf((WEX) + (TP).x);                              \
        const float c1_ = __expf((WEX) + (TP).y);                              \
        const float c2_ = __expf((WEX) + (TP).z);                              \
        const float c3_ = __expf((WEX) + (TP).w);                              \
        (M).x = (PV).x * c0_; (M).y = (PV).y * c1_;                            \
        (M).z = (PV).z * c2_; (M).w = (PV).w * c3_;                            \
        (R).x = __builtin_amdgcn_rcpf(fminf(fmaxf(c0_, EPSV), 1.0f));          \
        (R).y = __builtin_amdgcn_rcpf(fminf(fmaxf(c1_, EPSV), 1.0f));          \
        (R).z = __builtin_amdgcn_rcpf(fminf(fmaxf(c2_, EPSV), 1.0f));          \
        (R).w = __builtin_amdgcn_rcpf(fminf(fmaxf(c3_, EPSV), 1.0f));          \
    }

// ---------------------------------------------------------------------------
// alpha_echunk: FUSED kernel, 512 threads.
//  Blocks 0..7: alpha recurrence, R8's 2-steps-per-barrier structure (82.5us,
//    best of 7 tested) + CUMPROD FUSED IN (cumprod_mr kernel deleted):
//    the per-row cumsum of log(1-p) is row-independent parallel work. At pair
//    k each wave preps rows 2k+2/2k+3 (8 logs + 2 wave scans, fills the idle
//    VALU — VALUBusy was 5.8%), rides the existing slot/barrier with 2 extra
//    wave-totals, and post-barrier finishes cp=exp, m=p*cp, r=rcp(clip(cp))
//    into the registers the NEXT pair consumes. No new barriers; spine
//    unchanged. p is read in place of m/r (halves alpha's HBM reads) and
//    alpha OVERWRITES p row-by-row (per-thread slices disjoint; writes row
//    <= i+1, reads row >= i+2 -> race-free).
//  Blocks 8..519: e_chunk via G: e[b,h] = qg_h[b] @ kx[b]^T (K=512),
//    8-wave 128x256 tiles, under alpha's shadow.
//  smem 96 KB -> 1 block/CU isolation for alpha (+4% proven, kept).
// ---------------------------------------------------------------------------
__global__ __launch_bounds__(512, 1) void alpha_echunk(
    float* pa,                                   // in: p, out: alpha (in place)
    const unsigned short* __restrict__ qg, const unsigned short* __restrict__ kx,
    float* __restrict__ out)
{
    __shared__ __align__(16) char smem[98304];   // 96 KB -> 1 block/CU
    const int bid = blockIdx.x;
    const int tid = threadIdx.x;

    if (bid < BATCH) {
        // -------- alpha scan: 2 steps/barrier + fused cumprod --------
        __builtin_amdgcn_s_setprio(1);
        float (*slots)[4] = (float (*)[4])smem;          // [16][4] (par*8+wid)
        float* slotsB = (float*)(smem + 256);            // [16]
        const int lane = tid & 63, wid = tid >> 6;
        float* prow = pa + (size_t)bid * QLEN * KLEN + tid * 4;

        float aw0 = 0.f, aw1 = 0.f, aw2 = 0.f, aw3 = 0.f;
        if (tid == 0) aw0 = 1.0f;   // aw_prev one-hot at k=0

        float4 mA0, rA0, mA1, rA1, mB0, rB0, mB1, rB1;
        float4 pCa, pCb, pNa, pNb;

        // ---- prologue: m/r for rows 0,1 -> SET A; p rows 2..5 staged ----
        {
            float4 p0 = *(const float4*)(prow);
            float4 p1 = *(const float4*)(prow + KLEN);
            pCa = *(const float4*)(prow + 2 * (size_t)KLEN);
            pCb = *(const float4*)(prow + 3 * (size_t)KLEN);
            pNa = *(const float4*)(prow + 4 * (size_t)KLEN);
            pNb = *(const float4*)(prow + 5 * (size_t)KLEN);
            float4 tp0, tp1; float s0, s1;
            CUMPREP(p0, tp0, s0)
            CUMPREP(p1, tp1, s1)
            if (lane == 63) {
                float4 tv; tv.x = s0; tv.y = s1; tv.z = 0.f; tv.w = 0.f;
                *(float4*)(slots[8 + wid]) = tv;         // par=1 scratch area
            }
            lds_barrier();
            float4 tr = *(const float4*)(slots[8 + (lane & 7)]);
            const float px0 = row_prefix8(tr.x); const float e0x = px0 - tr.x;
            const float px1 = row_prefix8(tr.y); const float e1x = px1 - tr.y;
            const float wex0 = __shfl(e0x, wid);
            const float wex1 = __shfl(e1x, wid);
            CUMFIN(p0, tp0, wex0, mA0, rA0)
            CUMFIN(p1, tp1, wex1, mA1, rA1)
        }

#define APAIR(I, MC0, RC0, MC1, RC1, MN0, RN0, MN1, RN1)                       \
    {                                                                          \
        const int i_ = (I);                     /* even step index */          \
        const int par_ = (i_ >> 1) & 1;                                        \
        /* prep rows i_+2, i_+3 (row-independent; fills idle VALU) */          \
        float4 tpa_, tpb_; float sa_, sb_;                                     \
        CUMPREP(pCa, tpa_, sa_)                                                \
        CUMPREP(pCb, tpb_, sb_)                                                \
        /* step i: x = aw * r_i, within-wave prefix */                         \
        float run = 0.f, i0, i1, i2, i3;                                       \
        run = fmaf(aw0, RC0.x, run); i0 = run;                                 \
        run = fmaf(aw1, RC0.y, run); i1 = run;                                 \
        run = fmaf(aw2, RC0.z, run); i2 = run;                                 \
        run = fmaf(aw3, RC0.w, run); i3 = run;                                 \
        const float sx = wave_incl_scan(run);                                  \
        const float wb = sx - run;                                             \
        const float W0 = wb + i0, W1 = wb + i1, W2 = wb + i2, W3 = wb + i3;    \
        /* u = m_i * r_{i+1}; prefixes U (of u) and V (of u*W) */              \
        const float u0 = MC0.x * RC1.x, u1 = MC0.y * RC1.y;                    \
        const float u2 = MC0.z * RC1.z, u3 = MC0.w * RC1.w;                    \
        float ur = u0;       const float U0 = ur;                              \
        ur += u1;            const float U1 = ur;                              \
        ur += u2;            const float U2 = ur;                              \
        ur += u3;            const float U3 = ur;                              \
        const float sU = wave_incl_scan(ur);                                   \
        const float ub = sU - ur;                                              \
        float vr = u0 * W0;              const float V0 = vr;                  \
        vr = fmaf(u1, W1, vr);           const float V1 = vr;                  \
        vr = fmaf(u2, W2, vr);           const float V2 = vr;                  \
        vr = fmaf(u3, W3, vr);           const float V3 = vr;                  \
        const float sV = wave_incl_scan(vr);                                   \
        const float vb = sV - vr;                                              \
        if (lane == 63) {                                                      \
            float4 tv; tv.x = sx; tv.y = sU; tv.z = sV; tv.w = sa_;            \
            *(float4*)(slots[par_ * 8 + wid]) = tv;                            \
            slotsB[par_ * 8 + wid] = sb_;                                      \
        }                                                                      \
        lds_barrier();                                                         \
        float4 tr = *(const float4*)(slots[par_ * 8 + (lane & 7)]);            \
        const float trB = slotsB[par_ * 8 + (lane & 7)];                       \
        const float pT = row_prefix8(tr.x);                                    \
        const float Cex = pT - tr.x;                                           \
        const float t2 = fmaf(Cex, tr.y, tr.z);                                \
        const float pQ = row_prefix8(t2);                                      \
        const float C2ex = pQ - t2;                                            \
        float tw_ = tr.w;                                                      \
        const float pLa = row_prefix8(tw_);                                    \
        const float Laex = pLa - tr.w;                                         \
        float tb_ = trB;                                                       \
        const float pLb = row_prefix8(tb_);                                    \
        const float Lbex = pLb - trB;                                          \
        const float b0 = __shfl(Cex, wid);                                     \
        const float b1 = __shfl(C2ex, wid);                                    \
        const float wexa = __shfl(Laex, wid);                                  \
        const float wexb = __shfl(Lbex, wid);                                  \
        /* epilogue step i (alpha overwrites p row i_) */                      \
        float4 o0;                                                             \
        o0.x = MC0.x * (b0 + W0); o0.y = MC0.y * (b0 + W1);                    \
        o0.z = MC0.z * (b0 + W2); o0.w = MC0.w * (b0 + W3);                    \
        *(float4*)(prow + (size_t)i_ * KLEN) = o0;                             \
        /* epilogue step i+1 */                                                \
        const float X0 = fmaf(b0, ub + U0, vb + V0);                           \
        const float X1 = fmaf(b0, ub + U1, vb + V1);                           \
        const float X2 = fmaf(b0, ub + U2, vb + V2);                           \
        const float X3 = fmaf(b0, ub + U3, vb + V3);                           \
        aw0 = MC1.x * (b1 + X0); aw1 = MC1.y * (b1 + X1);                      \
        aw2 = MC1.z * (b1 + X2); aw3 = MC1.w * (b1 + X3);                      \
        float4 o1; o1.x = aw0; o1.y = aw1; o1.z = aw2; o1.w = aw3;             \
        *(float4*)(prow + (size_t)(i_ + 1) * KLEN) = o1;                       \
        /* finish cumprod for rows i_+2, i_+3 -> produce set */                \
        CUMFIN(pCa, tpa_, wexa, MN0, RN0)                                      \
        CUMFIN(pCb, tpb_, wexb, MN1, RN1)                                      \
        /* rotate p buffers; prefetch rows i_+6, i_+7 (clamped; rows > i_+1    \
           are still p — writes never outrun reads) */                         \
        pCa = pNa; pCb = pNb;                                                  \
        const int rla_ = (i_ + 6 < QLEN) ? (i_ + 6) : (QLEN - 1);              \
        const int rlb_ = (i_ + 7 < QLEN) ? (i_ + 7) : (QLEN - 1);              \
        pNa = *(const float4*)(prow + (size_t)rla_ * KLEN);                    \
        pNb = *(const float4*)(prow + (size_t)rlb_ * KLEN);                    \
    }

        for (int io = 0; io < QLEN; io += 4) {
            APAIR(io + 0, mA0, rA0, mA1, rA1, mB0, rB0, mB1, rB1)
            APAIR(io + 2, mB0, rB0, mB1, rB1, mA0, rA0, mA1, rA1)
        }
#undef APAIR
        __builtin_amdgcn_s_setprio(0);
        return;
    }

    // -------- echunk tile: 8 waves, 128x256, K=512 --------
    const int v = bid - BATCH;           // 0..511
    const int z = v >> 4;                // 0..31 = b*4+h
    const int rest = v & 15;
    const int by = rest >> 3;            // 0..1
    const int bx = rest & 7;             // 0..7
    const int b = z >> 2, h = z & 3;
    unsigned short* As = (unsigned short*)smem;             // 8 KB (128x32)
    unsigned short* Bs = (unsigned short*)(smem + 8192);    // 16 KB (256x32)
    const unsigned short* A = qg + (size_t)(b * QLEN) * GCOLS + 512 + h * 512;
    const unsigned short* B = kx + (size_t)b * KLEN * 512;
    const int bm = by * 128, bn = bx * 256;

    const int wv8 = tid >> 6, ln = tid & 63;
    const int r = ln & 15, quad = ln >> 4;
    const int wr = wv8 >> 2, wc = wv8 & 3;
    const int srow = tid >> 2;           // 0..127
    const int scol = (ln & 3) * 8;

    f32x4 acc[4][4]; zero_acc(acc);
    for (int ks = 0; ks < 16; ++ks) {
        const int k0 = ks * 32;
        gload_lds16(A + (size_t)(bm + srow) * GCOLS + k0 + scol,
                    As + (size_t)wv8 * 512);
        gload_lds16(B + (size_t)(bn + srow) * 512 + k0 + scol,
                    Bs + (size_t)wv8 * 512);
        gload_lds16(B + (size_t)(bn + 128 + srow) * 512 + k0 + scol,
                    Bs + 4096 + (size_t)wv8 * 512);
        __syncthreads();
        bf16x8 af[4], bg[4];
        #pragma unroll
        for (int f = 0; f < 4; ++f)
            af[f] = *(const bf16x8*)(As + (size_t)(wr * 64 + f * 16 + r) * 32 + quad * 8);
        #pragma unroll
        for (int f = 0; f < 4; ++f)
            bg[f] = *(const bf16x8*)(Bs + (size_t)(wc * 64 + f * 16 + r) * 32 + quad * 8);
        #pragma unroll
        for (int i = 0; i < 4; ++i)
            #pragma unroll
            for (int j2 = 0; j2 < 4; ++j2)
                acc[i][j2] = __builtin_amdgcn_mfma_f32_16x16x32_bf16(
                    af[i], bg[j2], acc[i][j2], 0, 0, 0);
        __syncthreads();
    }
    {
        const int m0 = bm + wr * 64, n0 = bn + wc * 64;
        #pragma unroll
        for (int i = 0; i < 4; ++i) {
            #pragma unroll
            for (int reg = 0; reg < 4; ++reg) {
                const int q = m0 + i * 16 + quad * 4 + reg;
                const size_t rowoff = ((size_t)z * QLEN + q) * KLEN;
                #pragma unroll
                for (int j = 0; j < 4; ++j) {
                    const int k = n0 + j * 16 + r;
                    out[rowoff + k] = acc[i][j][reg] * INV_SCALE;
                }
            }
        }
    }
}

// ---------------------------------------------------------------------------
// beta: per (b,h,q) row of 2048 (e_chunk in d_out, overwritten)
// ---------------------------------------------------------------------------
__global__ __launch_bounds__(256) void beta_kernel(
    float* __restrict__ eo, const float* __restrict__ alpha)
{
    __shared__ float sse[KLEN + 3];
    __shared__ float su[KLEN + 3];
    __shared__ float wmax[4];

    const int tid = threadIdx.x;
    const int lane = tid & 63, wid = tid >> 6;
    const int row = blockIdx.x;                 // [B*H*Q]
    const int q = row & (QLEN - 1);
    const int b = row >> 10;
    float* erow = eo + (size_t)row * KLEN;
    const float* arow = alpha + ((size_t)b * QLEN + q) * KLEN;

    if (tid < 3) { sse[tid] = 0.0f; su[KLEN + tid] = 0.0f; }

    float ev[8];
    float lm = -INFINITY;
    #pragma unroll
    for (int j = 0; j < 8; ++j) {
        const int k = tid + 256 * j;
        ev[j] = erow[k];
        lm = fmaxf(lm, ev[j]);
    }
    #pragma unroll
    for (int off = 32; off > 0; off >>= 1) lm = fmaxf(lm, __shfl_xor(lm, off));
    if (lane == 0) wmax[wid] = lm;
    __syncthreads();
    const float mx = fmaxf(fmaxf(wmax[0], wmax[1]), fmaxf(wmax[2], wmax[3]));

    #pragma unroll
    for (int j = 0; j < 8; ++j) {
        const int k = tid + 256 * j;
        sse[k + 3] = fmaxf(__expf(ev[j] - mx), 1e-5f);
    }
    __syncthreads();

    #pragma unroll
    for (int j = 0; j < 8; ++j) {
        const int k = tid + 256 * j;
        const float denom = sse[k + 3] + sse[k + 2] + sse[k + 1] + sse[k];
        su[k] = arow[k] * __builtin_amdgcn_rcpf(denom);
    }
    __syncthreads();

    #pragma unroll
    for (int j = 0; j < 8; ++j) {
        const int k = tid + 256 * j;
        erow[k] = sse[k + 3] * (su[k] + su[k + 1] + su[k + 2] + su[k + 3]);
    }
}

// ---------------------------------------------------------------------------
extern "C" void kernel_launch(void* const* d_in, const int* in_sizes, int n_in,
                              void* d_out, int out_size, void* d_ws, size_t ws_size,
                              hipStream_t stream)
{
    (void)in_sizes; (void)n_in; (void)out_size; (void)ws_size;
    const float* key_enc = (const float*)d_in[0];   // [8,2048,512]
    const float* query   = (const float*)d_in[1];   // [8,256,512]
    const float* noise   = (const float*)d_in[2];   // [8,256,2048]
    const float* Wk_m    = (const float*)d_in[3];
    const float* bk_m    = (const float*)d_in[4];
    const float* Wq_m    = (const float*)d_in[5];
    const float* bq_m    = (const float*)d_in[6];
    const float* rp      = (const float*)d_in[7];
    const float* Wk_c    = (const float*)d_in[8];
    const float* bk_c    = (const float*)d_in[9];
    const float* Wq_c    = (const float*)d_in[10];
    const float* bq_c    = (const float*)d_in[11];
    float* out = (float*)d_out;                     // [8,4,256,2048]
    (void)bk_c;

    // workspace layout (bytes)
    char* w = (char*)d_ws;
    unsigned short* kx   = (unsigned short*)w; w += (size_t)BATCH * KLEN * KDIM * 2;  // 16.8 MB
    unsigned short* qx   = (unsigned short*)w; w += (size_t)QROWS * KDIM * 2;         //  2.1 MB
    unsigned short* GT   = (unsigned short*)w; w += (size_t)GCOLS * 512 * 2;          //  2.6 MB
    unsigned short* qg   = (unsigned short*)w; w += (size_t)QROWS * GCOLS * 2;        // 10.5 MB
    float* aux    = (float*)w; w += 4096 * 4;
    float* vq2    = (float*)w; w += QROWS * 4;
    float* p_alpha = (float*)w;                     // p, overwritten with alpha

    // 1) casts + G matrices + bias folds (1 launch, was 2)
    hipLaunchKernelGGL(prep_g, dim3(NKXB + NQXB + 93), dim3(256), 0, stream,
                       key_enc, query, Wk_m, Wk_c, Wq_m, Wq_c,
                       bq_m, bk_m, bq_c, kx, qx, GT, aux);

    // 2) qg = qx @ GT^T + wv  (+ vq2)
    hipLaunchKernelGGL(qg_kernel, dim3(328), dim3(256), 0, stream,
                       qx, GT, aux, qg, vq2);

    // 3) p_choose
    hipLaunchKernelGGL(pchoose_mfma, dim3(KLEN / 128, QLEN / 128, BATCH), dim3(256), 0, stream,
                       qg, kx, noise, rp, vq2, p_alpha);

    // 4) FUSED: alpha recurrence with in-kernel cumprod (blocks 0..7) +
    //           e_chunk (blocks 8..519). cumprod_mr kernel deleted.
    hipLaunchKernelGGL(alpha_echunk, dim3(BATCH + 512), dim3(512), 0, stream,
                       p_alpha, qg, kx, out);

    // 5) beta (overwrites e_chunk rows in d_out)
    hipLaunchKernelGGL(beta_kernel, dim3(BATCH * NHEADS * QLEN), dim3(256), 0, stream,
                       out, p_alpha);
}

// Round 10
// 283.923 us; speedup vs baseline: 1.2528x; 1.2528x over previous
//
#include <hip/hip_runtime.h>
#include <math.h>

// Problem constants
#define BATCH   8
#define QLEN    256
#define KLEN    2048
#define KDIM    512
#define NHEADS  4
#define DKH     128
#define NG      5                       // mono + 4 heads
#define QROWS   (BATCH * QLEN)          // 2048
#define GCOLS   (NG * 512)              // 2560

static constexpr float INV_SCALE = 0.04419417382415922f; // 1/sqrt(512)
static constexpr float EPSV = 1e-6f;

typedef __attribute__((ext_vector_type(8))) short bf16x8;
typedef __attribute__((ext_vector_type(4))) float f32x4;

__device__ __forceinline__ unsigned short f2bf(float f) {
    unsigned u = __builtin_bit_cast(unsigned, f);
    u += 0x7fffu + ((u >> 16) & 1u);   // round-to-nearest-even
    return (unsigned short)(u >> 16);
}
__device__ __forceinline__ float bf2f(unsigned short u) {
    unsigned x = (unsigned)u << 16;
    return __builtin_bit_cast(float, x);
}

// Barrier waiting only on LDS ops (lgkmcnt); global loads/stores stay in flight.
__device__ __forceinline__ void lds_barrier() {
    __asm__ volatile("s_waitcnt lgkmcnt(0)\n\ts_barrier" ::: "memory");
}

// Async global->LDS, 16 B per lane (wave-uniform base + lane*16 rule).
__device__ __forceinline__ void gload_lds16(const void* g, void* l) {
    __builtin_amdgcn_global_load_lds(
        (const __attribute__((address_space(1))) void*)g,
        (__attribute__((address_space(3))) void*)l, 16, 0, 0);
}

// ---------------------------------------------------------------------------
// Staged NT MFMA core (bf16 inputs via global_load_lds): 128x128 f32 tile.
// 256 threads / 4 waves, each wave a 64x64 subtile.
// ---------------------------------------------------------------------------
__device__ __forceinline__ void mfma_nt_staged(
    const unsigned short* __restrict__ A, const unsigned short* __restrict__ B,
    int lda, int ldb, int bm, int bn,
    unsigned short* AsLDS, unsigned short* BsLDS, f32x4 acc[4][4], int ksteps)
{
    const int t = threadIdx.x;
    const int wv = t >> 6, ln = t & 63;
    const int r = ln & 15, quad = ln >> 4;
    const int wm = (wv >> 1) * 64, wn = (wv & 1) * 64;
    const int srow = wv * 16 + (ln >> 2);
    const int scol = (ln & 3) * 8;

    for (int ks = 0; ks < ksteps; ++ks) {
        const int k0 = ks * 32;
        #pragma unroll
        for (int j = 0; j < 2; ++j) {
            gload_lds16(A + (size_t)(bm + j * 64 + srow) * lda + k0 + scol,
                        AsLDS + (size_t)(j * 64 + wv * 16) * 32);
            gload_lds16(B + (size_t)(bn + j * 64 + srow) * ldb + k0 + scol,
                        BsLDS + (size_t)(j * 64 + wv * 16) * 32);
        }
        __syncthreads();
        bf16x8 af[4], bg[4];
        #pragma unroll
        for (int f = 0; f < 4; ++f)
            af[f] = *(const bf16x8*)(AsLDS + (size_t)(wm + f * 16 + r) * 32 + quad * 8);
        #pragma unroll
        for (int f = 0; f < 4; ++f)
            bg[f] = *(const bf16x8*)(BsLDS + (size_t)(wn + f * 16 + r) * 32 + quad * 8);
        #pragma unroll
        for (int i = 0; i < 4; ++i)
            #pragma unroll
            for (int j2 = 0; j2 < 4; ++j2)
                acc[i][j2] = __builtin_amdgcn_mfma_f32_16x16x32_bf16(
                    af[i], bg[j2], acc[i][j2], 0, 0, 0);
        __syncthreads();
    }
}

// Same core but A/B are f32 in HBM; staged via reg-cast (f2bf) + ds_write_b128.
// Produces bit-identical bf16 operands to the pre-cast path.
__device__ __forceinline__ void mfma_nt_staged_f32(
    const float* __restrict__ A, const float* __restrict__ B,
    int lda, int ldb, int bm, int bn,
    unsigned short* AsLDS, unsigned short* BsLDS, f32x4 acc[4][4], int ksteps)
{
    const int t = threadIdx.x;
    const int wv = t >> 6, ln = t & 63;
    const int r = ln & 15, quad = ln >> 4;
    const int wm = (wv >> 1) * 64, wn = (wv & 1) * 64;
    const int srow = wv * 16 + (ln >> 2);
    const int scol = (ln & 3) * 8;

    for (int ks = 0; ks < ksteps; ++ks) {
        const int k0 = ks * 32;
        #pragma unroll
        for (int j = 0; j < 2; ++j) {
            const float* ap = A + (size_t)(bm + j * 64 + srow) * lda + k0 + scol;
            float4 a0 = *(const float4*)ap, a1 = *(const float4*)(ap + 4);
            bf16x8 av;
            av[0] = (short)f2bf(a0.x); av[1] = (short)f2bf(a0.y);
            av[2] = (short)f2bf(a0.z); av[3] = (short)f2bf(a0.w);
            av[4] = (short)f2bf(a1.x); av[5] = (short)f2bf(a1.y);
            av[6] = (short)f2bf(a1.z); av[7] = (short)f2bf(a1.w);
            *(bf16x8*)(AsLDS + (size_t)(j * 64 + wv * 16) * 32 + ln * 8) = av;
            const float* bp = B + (size_t)(bn + j * 64 + srow) * ldb + k0 + scol;
            float4 b0 = *(const float4*)bp, b1 = *(const float4*)(bp + 4);
            bf16x8 bv;
            bv[0] = (short)f2bf(b0.x); bv[1] = (short)f2bf(b0.y);
            bv[2] = (short)f2bf(b0.z); bv[3] = (short)f2bf(b0.w);
            bv[4] = (short)f2bf(b1.x); bv[5] = (short)f2bf(b1.y);
            bv[6] = (short)f2bf(b1.z); bv[7] = (short)f2bf(b1.w);
            *(bf16x8*)(BsLDS + (size_t)(j * 64 + wv * 16) * 32 + ln * 8) = bv;
        }
        __syncthreads();
        bf16x8 af[4], bg[4];
        #pragma unroll
        for (int f = 0; f < 4; ++f)
            af[f] = *(const bf16x8*)(AsLDS + (size_t)(wm + f * 16 + r) * 32 + quad * 8);
        #pragma unroll
        for (int f = 0; f < 4; ++f)
            bg[f] = *(const bf16x8*)(BsLDS + (size_t)(wn + f * 16 + r) * 32 + quad * 8);
        #pragma unroll
        for (int i = 0; i < 4; ++i)
            #pragma unroll
            for (int j2 = 0; j2 < 4; ++j2)
                acc[i][j2] = __builtin_amdgcn_mfma_f32_16x16x32_bf16(
                    af[i], bg[j2], acc[i][j2], 0, 0, 0);
        __syncthreads();
    }
}

__device__ __forceinline__ void zero_acc(f32x4 acc[4][4]) {
    #pragma unroll
    for (int i = 0; i < 4; ++i)
        #pragma unroll
        for (int j = 0; j < 4; ++j)
            acc[i][j] = f32x4{0.f, 0.f, 0.f, 0.f};
}

// ---------------------------------------------------------------------------
// prep_g: input casts + G matrices + bias-fold vectors, ONE launch.
//  blocks [0, 8192)        cast key_enc -> kx (bf16)
//  blocks [8192, 9216)     cast query   -> qx (bf16)
//  blocks [9216, 9296)     G-matrix tiles (f32-staged MFMA; same f2bf rounding)
//  blocks [9296, 9309)     aux bias-fold vectors
// ---------------------------------------------------------------------------
#define NKXB 8192
#define NQXB 1024
__global__ __launch_bounds__(256) void prep_g(
    const float* __restrict__ key_enc, const float* __restrict__ query,
    const float* __restrict__ Wk_m, const float* __restrict__ Wk_c,
    const float* __restrict__ Wq_m, const float* __restrict__ Wq_c,
    const float* __restrict__ bq_m, const float* __restrict__ bk_m,
    const float* __restrict__ bq_c,
    unsigned short* __restrict__ kx, unsigned short* __restrict__ qx,
    unsigned short* __restrict__ GT, float* __restrict__ aux)
{
    __shared__ unsigned short As[128 * 32];
    __shared__ unsigned short Bs[128 * 32];
    __shared__ float red[256];
    const int gb = blockIdx.x, tid = threadIdx.x;

    if (gb < NKXB + NQXB) {
        const float* x = (gb < NKXB) ? key_enc : query;
        unsigned short* y = (gb < NKXB) ? kx : qx;
        const int i = (gb < NKXB ? gb : gb - NKXB) * 256 + tid;
        float4 v = ((const float4*)x)[i];
        ushort4 o;
        o.x = f2bf(v.x); o.y = f2bf(v.y); o.z = f2bf(v.z); o.w = f2bf(v.w);
        ((ushort4*)y)[i] = o;
        return;
    }
    const int t = gb - NKXB - NQXB;          // 0..92
    if (t < 80) {
        const int seg = t >> 4, tt = t & 15;
        const int bm = (tt >> 2) * 128, bn = (tt & 3) * 128;
        const float *A, *B; int ks;
        if (seg == 0) { A = Wk_m; B = Wq_m; ks = 16; }
        else { const int h = seg - 1; A = Wk_c + h * 128; B = Wq_c + h * 128; ks = 4; }
        f32x4 acc[4][4]; zero_acc(acc);
        mfma_nt_staged_f32(A, B, 512, 512, bm, bn, As, Bs, acc, ks);
        const int wv = tid >> 6, ln = tid & 63;
        const int r = ln & 15, quad = ln >> 4;
        const int m0 = bm + (wv >> 1) * 64, n0 = bn + (wv & 1) * 64;
        #pragma unroll
        for (int j = 0; j < 4; ++j) {
            const int n = n0 + j * 16 + r;
            #pragma unroll
            for (int i = 0; i < 4; ++i)
                #pragma unroll
                for (int reg = 0; reg < 4; ++reg) {
                    const int m = m0 + i * 16 + quad * 4 + reg;
                    GT[(size_t)(seg * 512 + m) * 512 + n] = f2bf(acc[i][j][reg]);
                }
        }
        return;
    }
    const int ab = t - 80;
    if (ab < 2) {                       // mono wv: Wk_m @ bq_m
        const int d = ab * 256 + tid;
        const float* row = Wk_m + (size_t)d * 512;
        float s = 0.f;
        for (int j = 0; j < 512; j += 4) {
            float4 a = *(const float4*)(row + j);
            float4 b = *(const float4*)(bq_m + j);
            s += a.x * b.x + a.y * b.y + a.z * b.z + a.w * b.w;
        }
        aux[d] = s; return;
    }
    if (ab < 10) {                      // head wv: Wk_c[:,h-slice] @ bq_c[h-slice]
        const int tt = ab - 2, h = tt >> 1;
        const int d = (tt & 1) * 256 + tid;
        const float* row = Wk_c + (size_t)d * 512 + h * 128;
        const float* bv = bq_c + h * 128;
        float s = 0.f;
        for (int j = 0; j < 128; j += 4) {
            float4 a = *(const float4*)(row + j);
            float4 b = *(const float4*)(bv + j);
            s += a.x * b.x + a.y * b.y + a.z * b.z + a.w * b.w;
        }
        aux[512 + h * 512 + d] = s; return;
    }
    if (ab < 12) {                      // wu: Wq_m @ bk_m
        const int d = (ab - 10) * 256 + tid;
        const float* row = Wq_m + (size_t)d * 512;
        float s = 0.f;
        for (int j = 0; j < 512; j += 4) {
            float4 a = *(const float4*)(row + j);
            float4 b = *(const float4*)(bk_m + j);
            s += a.x * b.x + a.y * b.y + a.z * b.z + a.w * b.w;
        }
        aux[GCOLS + d] = s; return;
    }
    // cc = dot(bq_m, bk_m)
    float s = bq_m[tid] * bk_m[tid] + bq_m[tid + 256] * bk_m[tid + 256];
    red[tid] = s; __syncthreads();
    for (int o = 128; o > 0; o >>= 1) {
        if (tid < o) red[tid] += red[tid + o];
        __syncthreads();
    }
    if (tid == 0) aux[GCOLS + 512] = red[0];
}

// ---------------------------------------------------------------------------
// qg_kernel: qg[2048][2560] bf16 = qx @ GT^T + wv  (NT, K=512).
// Blocks 0..319: 128x128 tiles. Blocks 320..327: vq2[q] = (qx[q].wu + cc)/scale.
// ---------------------------------------------------------------------------
__global__ __launch_bounds__(256) void qg_kernel(
    const unsigned short* __restrict__ qx, const unsigned short* __restrict__ GT,
    const float* __restrict__ aux,
    unsigned short* __restrict__ qg, float* __restrict__ vq2)
{
    __shared__ unsigned short As[128 * 32];
    __shared__ unsigned short Bs[128 * 32];
    __shared__ float wuS[512];
    const int v = blockIdx.x, tid = threadIdx.x;
    if (v < 320) {
        const int by = v / 20, bx = v % 20;
        const int bm = by * 128, bn = bx * 128;
        f32x4 acc[4][4]; zero_acc(acc);
        mfma_nt_staged(qx, GT, 512, 512, bm, bn, As, Bs, acc, 16);
        const int wv = tid >> 6, ln = tid & 63;
        const int r = ln & 15, quad = ln >> 4;
        const int m0 = bm + (wv >> 1) * 64, n0 = bn + (wv & 1) * 64;
        #pragma unroll
        for (int j = 0; j < 4; ++j) {
            const int n = n0 + j * 16 + r;
            const float wvb = aux[n];
            #pragma unroll
            for (int i = 0; i < 4; ++i)
                #pragma unroll
                for (int reg = 0; reg < 4; ++reg) {
                    const int m = m0 + i * 16 + quad * 4 + reg;
                    qg[(size_t)m * GCOLS + n] = f2bf(acc[i][j][reg] + wvb);
                }
        }
        return;
    }
    // vq2
    wuS[tid] = aux[GCOLS + tid];
    wuS[tid + 256] = aux[GCOLS + tid + 256];
    __syncthreads();
    const float cc = aux[GCOLS + 512];
    const int q = (v - 320) * 256 + tid;
    const unsigned short* row = qx + (size_t)q * 512;
    float s = 0.f;
    for (int j = 0; j < 512; j += 4) {
        ushort4 a = *(const ushort4*)(row + j);
        s = fmaf(bf2f(a.x), wuS[j], s);
        s = fmaf(bf2f(a.y), wuS[j + 1], s);
        s = fmaf(bf2f(a.z), wuS[j + 2], s);
        s = fmaf(bf2f(a.w), wuS[j + 3], s);
    }
    vq2[q] = (s + cc) * INV_SCALE;
}

// ---------------------------------------------------------------------------
// p_choose: p = sigmoid(qg_mono[b] @ kx[b]^T / scale + vq2 + r + noise)
// ---------------------------------------------------------------------------
__global__ __launch_bounds__(256) void pchoose_mfma(
    const unsigned short* __restrict__ qg, const unsigned short* __restrict__ kx,
    const float* __restrict__ noise, const float* __restrict__ rp,
    const float* __restrict__ vq2, float* __restrict__ p)
{
    __shared__ unsigned short As[128 * 32];
    __shared__ unsigned short Bs[128 * 32];
    const int b = blockIdx.z;
    const unsigned short* A = qg + (size_t)b * QLEN * GCOLS;      // mono cols 0..512
    const unsigned short* B = kx + (size_t)b * KLEN * 512;
    const int bm = blockIdx.y * 128, bn = blockIdx.x * 128;
    f32x4 acc[4][4]; zero_acc(acc);
    mfma_nt_staged(A, B, GCOLS, 512, bm, bn, As, Bs, acc, 16);
    const int wv = threadIdx.x >> 6, ln = threadIdx.x & 63;
    const int r = ln & 15, quad = ln >> 4;
    const int m0 = bm + (wv >> 1) * 64, n0 = bn + (wv & 1) * 64;
    const float rv = rp[0];
    #pragma unroll
    for (int i = 0; i < 4; ++i) {
        #pragma unroll
        for (int reg = 0; reg < 4; ++reg) {
            const int q = m0 + i * 16 + quad * 4 + reg;
            const size_t rowoff = ((size_t)b * QLEN + q) * KLEN;
            const float vq = vq2[b * QLEN + q] + rv;
            #pragma unroll
            for (int j = 0; j < 4; ++j) {
                const int k = n0 + j * 16 + r;
                const float e = acc[i][j][reg] * INV_SCALE + vq + noise[rowoff + k];
                p[rowoff + k] = __builtin_amdgcn_rcpf(1.0f + __expf(-e));
            }
        }
    }
}

// ---------------------------------------------------------------------------
// 64-lane inclusive prefix sum via DPP (≈6 VALU ops)
// ---------------------------------------------------------------------------
__device__ __forceinline__ float wave_incl_scan(float x)
{
#define DPP_ADD(ctrl, rmask, bctrl)                                            \
    { int _t = __builtin_amdgcn_update_dpp(0, __builtin_bit_cast(int, x),      \
                                           ctrl, rmask, 0xf, bctrl);           \
      x += __builtin_bit_cast(float, _t); }
    DPP_ADD(0x111, 0xf, true)   // row_shr:1
    DPP_ADD(0x112, 0xf, true)   // row_shr:2
    DPP_ADD(0x114, 0xf, true)   // row_shr:4
    DPP_ADD(0x118, 0xf, true)   // row_shr:8
    DPP_ADD(0x142, 0xa, false)  // row_bcast:15 -> rows 1,3
    DPP_ADD(0x143, 0xc, false)  // row_bcast:31 -> rows 2,3
#undef DPP_ADD
    return x;
}

// Inclusive prefix over lanes 0..7 (valid in those lanes only; row_shr DPP).
__device__ __forceinline__ float row_prefix8(float x)
{
#define DPP_ADD(ctrl)                                                          \
    { int _t = __builtin_amdgcn_update_dpp(0, __builtin_bit_cast(int, x),      \
                                           ctrl, 0xf, 0xf, true);              \
      x += __builtin_bit_cast(float, _t); }
    DPP_ADD(0x111)   // row_shr:1
    DPP_ADD(0x112)   // row_shr:2
    DPP_ADD(0x114)   // row_shr:4
#undef DPP_ADD
    return x;
}

// ---------------------------------------------------------------------------
// cumprod_mr: per (b,q) row: cp = exp(excl_cumsum(log(clip(1-p)))); emits
// m = p*cp, r = 1/clip(cp). RESTORED as standalone kernel (R9 lesson: fusing
// this into the barrier-paced alpha loop put its transcendentals on the
// serial spine and doubled alpha's time; as a parallel kernel it costs ~10us).
// ---------------------------------------------------------------------------
__global__ __launch_bounds__(256) void cumprod_mr(
    const float* __restrict__ p, float* __restrict__ mArr, float* __restrict__ rArr)
{
    const size_t row = blockIdx.x;
    const float* pr = p + row * KLEN;
    float* mr = mArr + row * KLEN;
    float* rr = rArr + row * KLEN;
    const int tid = threadIdx.x;
    const int lane = tid & 63, wid = tid >> 6;
    __shared__ float waveTot[4];

    float4 v0 = *(const float4*)(pr + tid * 8);
    float4 v1 = *(const float4*)(pr + tid * 8 + 4);
    float pv[8] = {v0.x, v0.y, v0.z, v0.w, v1.x, v1.y, v1.z, v1.w};
    float excl[8];
    float run = 0.0f;
    #pragma unroll
    for (int j = 0; j < 8; ++j) {
        float l = __logf(fminf(fmaxf(1.0f - pv[j], EPSV), 1.0f));
        excl[j] = run;
        run += l;
    }
    float s = wave_incl_scan(run);
    if (lane == 63) waveTot[wid] = s;
    __syncthreads();
    float wex = 0.0f;
    for (int w = 0; w < wid; ++w) wex += waveTot[w];
    const float texcl = wex + s - run;

    float mv[8], rv[8];
    #pragma unroll
    for (int j = 0; j < 8; ++j) {
        const float cpv = __expf(texcl + excl[j]);
        mv[j] = pv[j] * cpv;
        rv[j] = __builtin_amdgcn_rcpf(fminf(fmaxf(cpv, EPSV), 1.0f));
    }
    *(float4*)(mr + tid * 8)     = *(float4*)&mv[0];
    *(float4*)(mr + tid * 8 + 4) = *(float4*)&mv[4];
    *(float4*)(rr + tid * 8)     = *(float4*)&rv[0];
    *(float4*)(rr + tid * 8 + 4) = *(float4*)&rv[4];
}

// ---------------------------------------------------------------------------
// alpha_echunk: FUSED kernel, 512 threads. R8 form restored (best: 82.5us).
//  Blocks 0..7: alpha recurrence, TWO STEPS PER BARRIER (see R8 notes).
//  Blocks 8..519: e_chunk via G: e[b,h] = qg_h[b] @ kx[b]^T (K=512),
//    8-wave 128x256 tiles, under alpha's shadow.
//  smem 96 KB -> 1 block/CU isolation for alpha. setprio kept.
//  R9 lesson encoded: do NOT add work inside the barrier-paced loop — any
//  in-loop addition is serial time regardless of idle-looking VALU counters.
// ---------------------------------------------------------------------------
__global__ __launch_bounds__(512, 1) void alpha_echunk(
    const float* __restrict__ mArr, const float* __restrict__ rArr,
    float* __restrict__ alpha,
    const unsigned short* __restrict__ qg, const unsigned short* __restrict__ kx,
    float* __restrict__ out)
{
    __shared__ __align__(16) char smem[98304];   // 96 KB -> 1 block/CU
    const int bid = blockIdx.x;
    const int tid = threadIdx.x;

    if (bid < BATCH) {
        // -------- alpha scan: 2 steps per barrier --------
        __builtin_amdgcn_s_setprio(1);
        float* slots = (float*)smem;             // [2][8][4] floats
        const int lane = tid & 63, wid = tid >> 6;
        const float* mrow = mArr + (size_t)bid * QLEN * KLEN + tid * 4;
        const float* rrow = rArr + (size_t)bid * QLEN * KLEN + tid * 4;
        float* arow = alpha + (size_t)bid * QLEN * KLEN + tid * 4;

        float aw0 = 0.f, aw1 = 0.f, aw2 = 0.f, aw3 = 0.f;
        if (tid == 0) aw0 = 1.0f;   // aw_prev one-hot at k=0

        // set A = pair rows (0,1); set B = pair rows (2,3)
        float4 mP0 = *(const float4*)(mrow);
        float4 rP0 = *(const float4*)(rrow);
        float4 mP1 = *(const float4*)(mrow + KLEN);
        float4 rP1 = *(const float4*)(rrow + KLEN);
        float4 mQ0 = *(const float4*)(mrow + 2 * (size_t)KLEN);
        float4 rQ0 = *(const float4*)(rrow + 2 * (size_t)KLEN);
        float4 mQ1 = *(const float4*)(mrow + 3 * (size_t)KLEN);
        float4 rQ1 = *(const float4*)(rrow + 3 * (size_t)KLEN);

#define APAIR(I, M0, R0, M1, R1)                                               \
    {                                                                          \
        const int i_ = (I);                     /* even step index */          \
        float4 mc0 = M0, rc0 = R0, mc1 = M1, rc1 = R1;                         \
        const int rn_ = (i_ + 4 < QLEN) ? (i_ + 4) : (QLEN - 2);               \
        M0 = *(const float4*)(mrow + (size_t)rn_ * KLEN);                      \
        R0 = *(const float4*)(rrow + (size_t)rn_ * KLEN);                      \
        M1 = *(const float4*)(mrow + (size_t)(rn_ + 1) * KLEN);               \
        R1 = *(const float4*)(rrow + (size_t)(rn_ + 1) * KLEN);               \
        /* step i: x = aw * r_i, within-wave prefix */                         \
        float run = 0.f, i0, i1, i2, i3;                                       \
        run = fmaf(aw0, rc0.x, run); i0 = run;                                 \
        run = fmaf(aw1, rc0.y, run); i1 = run;                                 \
        run = fmaf(aw2, rc0.z, run); i2 = run;                                 \
        run = fmaf(aw3, rc0.w, run); i3 = run;                                 \
        const float sx = wave_incl_scan(run);                                  \
        const float wb = sx - run;                                             \
        const float W0 = wb + i0, W1 = wb + i1, W2 = wb + i2, W3 = wb + i3;    \
        /* u = m_i * r_{i+1}; prefixes U (of u) and V (of u*W) */              \
        const float u0 = mc0.x * rc1.x, u1 = mc0.y * rc1.y;                    \
        const float u2 = mc0.z * rc1.z, u3 = mc0.w * rc1.w;                    \
        float ur = u0;       const float U0 = ur;                              \
        ur += u1;            const float U1 = ur;                              \
        ur += u2;            const float U2 = ur;                              \
        ur += u3;            const float U3 = ur;                              \
        const float sU = wave_incl_scan(ur);                                   \
        const float ub = sU - ur;                                              \
        float vr = u0 * W0;              const float V0 = vr;                  \
        vr = fmaf(u1, W1, vr);           const float V1 = vr;                  \
        vr = fmaf(u2, W2, vr);           const float V2 = vr;                  \
        vr = fmaf(u3, W3, vr);           const float V3 = vr;                  \
        const float sV = wave_incl_scan(vr);                                   \
        const float vb = sV - vr;                                              \
        const int par = (i_ >> 1) & 1;                                         \
        if (lane == 63) {                                                      \
            float4 tv; tv.x = sx; tv.y = sU; tv.z = sV; tv.w = 0.f;            \
            *(float4*)(slots + (par * 8 + wid) * 4) = tv;                      \
        }                                                                      \
        lds_barrier();                                                         \
        float4 tr = *(const float4*)(slots + (par * 8 + (lane & 7)) * 4);      \
        const float pT = row_prefix8(tr.x);                                    \
        const float Cex = pT - tr.x;                                           \
        const float t2 = fmaf(Cex, tr.y, tr.z);                                \
        const float pQ = row_prefix8(t2);                                      \
        const float C2ex = pQ - t2;                                            \
        const float b0 = __shfl(Cex, wid);                                     \
        const float b1 = __shfl(C2ex, wid);                                    \
        /* epilogue step i */                                                  \
        float4 o0;                                                             \
        o0.x = mc0.x * (b0 + W0); o0.y = mc0.y * (b0 + W1);                    \
        o0.z = mc0.z * (b0 + W2); o0.w = mc0.w * (b0 + W3);                    \
        *(float4*)(arow + (size_t)i_ * KLEN) = o0;                             \
        /* epilogue step i+1 */                                                \
        const float X0 = fmaf(b0, ub + U0, vb + V0);                           \
        const float X1 = fmaf(b0, ub + U1, vb + V1);                           \
        const float X2 = fmaf(b0, ub + U2, vb + V2);                           \
        const float X3 = fmaf(b0, ub + U3, vb + V3);                           \
        aw0 = mc1.x * (b1 + X0); aw1 = mc1.y * (b1 + X1);                      \
        aw2 = mc1.z * (b1 + X2); aw3 = mc1.w * (b1 + X3);                      \
        float4 o1; o1.x = aw0; o1.y = aw1; o1.z = aw2; o1.w = aw3;             \
        *(float4*)(arow + (size_t)(i_ + 1) * KLEN) = o1;                       \
    }

        for (int io = 0; io < QLEN; io += 4) {
            APAIR(io + 0, mP0, rP0, mP1, rP1)
            APAIR(io + 2, mQ0, rQ0, mQ1, rQ1)
        }
#undef APAIR
        __builtin_amdgcn_s_setprio(0);
        return;
    }

    // -------- echunk tile: 8 waves, 128x256, K=512 --------
    const int v = bid - BATCH;           // 0..511
    const int z = v >> 4;                // 0..31 = b*4+h
    const int rest = v & 15;
    const int by = rest >> 3;            // 0..1
    const int bx = rest & 7;             // 0..7
    const int b = z >> 2, h = z & 3;
    unsigned short* As = (unsigned short*)smem;             // 8 KB (128x32)
    unsigned short* Bs = (unsigned short*)(smem + 8192);    // 16 KB (256x32)
    const unsigned short* A = qg + (size_t)(b * QLEN) * GCOLS + 512 + h * 512;
    const unsigned short* B = kx + (size_t)b * KLEN * 512;
    const int bm = by * 128, bn = bx * 256;

    const int wv8 = tid >> 6, ln = tid & 63;
    const int r = ln & 15, quad = ln >> 4;
    const int wr = wv8 >> 2, wc = wv8 & 3;
    const int srow = tid >> 2;           // 0..127
    const int scol = (ln & 3) * 8;

    f32x4 acc[4][4]; zero_acc(acc);
    for (int ks = 0; ks < 16; ++ks) {
        const int k0 = ks * 32;
        gload_lds16(A + (size_t)(bm + srow) * GCOLS + k0 + scol,
                    As + (size_t)wv8 * 512);
        gload_lds16(B + (size_t)(bn + srow) * 512 + k0 + scol,
                    Bs + (size_t)wv8 * 512);
        gload_lds16(B + (size_t)(bn + 128 + srow) * 512 + k0 + scol,
                    Bs + 4096 + (size_t)wv8 * 512);
        __syncthreads();
        bf16x8 af[4], bg[4];
        #pragma unroll
        for (int f = 0; f < 4; ++f)
            af[f] = *(const bf16x8*)(As + (size_t)(wr * 64 + f * 16 + r) * 32 + quad * 8);
        #pragma unroll
        for (int f = 0; f < 4; ++f)
            bg[f] = *(const bf16x8*)(Bs + (size_t)(wc * 64 + f * 16 + r) * 32 + quad * 8);
        #pragma unroll
        for (int i = 0; i < 4; ++i)
            #pragma unroll
            for (int j2 = 0; j2 < 4; ++j2)
                acc[i][j2] = __builtin_amdgcn_mfma_f32_16x16x32_bf16(
                    af[i], bg[j2], acc[i][j2], 0, 0, 0);
        __syncthreads();
    }
    {
        const int m0 = bm + wr * 64, n0 = bn + wc * 64;
        #pragma unroll
        for (int i = 0; i < 4; ++i) {
            #pragma unroll
            for (int reg = 0; reg < 4; ++reg) {
                const int q = m0 + i * 16 + quad * 4 + reg;
                const size_t rowoff = ((size_t)z * QLEN + q) * KLEN;
                #pragma unroll
                for (int j = 0; j < 4; ++j) {
                    const int k = n0 + j * 16 + r;
                    out[rowoff + k] = acc[i][j][reg] * INV_SCALE;
                }
            }
        }
    }
}

// ---------------------------------------------------------------------------
// beta: per (b,h,q) row of 2048 (e_chunk in d_out, overwritten)
// ---------------------------------------------------------------------------
__global__ __launch_bounds__(256) void beta_kernel(
    float* __restrict__ eo, const float* __restrict__ alpha)
{
    __shared__ float sse[KLEN + 3];
    __shared__ float su[KLEN + 3];
    __shared__ float wmax[4];

    const int tid = threadIdx.x;
    const int lane = tid & 63, wid = tid >> 6;
    const int row = blockIdx.x;                 // [B*H*Q]
    const int q = row & (QLEN - 1);
    const int b = row >> 10;
    float* erow = eo + (size_t)row * KLEN;
    const float* arow = alpha + ((size_t)b * QLEN + q) * KLEN;

    if (tid < 3) { sse[tid] = 0.0f; su[KLEN + tid] = 0.0f; }

    float ev[8];
    float lm = -INFINITY;
    #pragma unroll
    for (int j = 0; j < 8; ++j) {
        const int k = tid + 256 * j;
        ev[j] = erow[k];
        lm = fmaxf(lm, ev[j]);
    }
    #pragma unroll
    for (int off = 32; off > 0; off >>= 1) lm = fmaxf(lm, __shfl_xor(lm, off));
    if (lane == 0) wmax[wid] = lm;
    __syncthreads();
    const float mx = fmaxf(fmaxf(wmax[0], wmax[1]), fmaxf(wmax[2], wmax[3]));

    #pragma unroll
    for (int j = 0; j < 8; ++j) {
        const int k = tid + 256 * j;
        sse[k + 3] = fmaxf(__expf(ev[j] - mx), 1e-5f);
    }
    __syncthreads();

    #pragma unroll
    for (int j = 0; j < 8; ++j) {
        const int k = tid + 256 * j;
        const float denom = sse[k + 3] + sse[k + 2] + sse[k + 1] + sse[k];
        su[k] = arow[k] * __builtin_amdgcn_rcpf(denom);
    }
    __syncthreads();

    #pragma unroll
    for (int j = 0; j < 8; ++j) {
        const int k = tid + 256 * j;
        erow[k] = sse[k + 3] * (su[k] + su[k + 1] + su[k + 2] + su[k + 3]);
    }
}

// ---------------------------------------------------------------------------
extern "C" void kernel_launch(void* const* d_in, const int* in_sizes, int n_in,
                              void* d_out, int out_size, void* d_ws, size_t ws_size,
                              hipStream_t stream)
{
    (void)in_sizes; (void)n_in; (void)out_size; (void)ws_size;
    const float* key_enc = (const float*)d_in[0];   // [8,2048,512]
    const float* query   = (const float*)d_in[1];   // [8,256,512]
    const float* noise   = (const float*)d_in[2];   // [8,256,2048]
    const float* Wk_m    = (const float*)d_in[3];
    const float* bk_m    = (const float*)d_in[4];
    const float* Wq_m    = (const float*)d_in[5];
    const float* bq_m    = (const float*)d_in[6];
    const float* rp      = (const float*)d_in[7];
    const float* Wk_c    = (const float*)d_in[8];
    const float* bk_c    = (const float*)d_in[9];
    const float* Wq_c    = (const float*)d_in[10];
    const float* bq_c    = (const float*)d_in[11];
    float* out = (float*)d_out;                     // [8,4,256,2048]
    (void)bk_c;

    // workspace layout (bytes)
    char* w = (char*)d_ws;
    unsigned short* kx   = (unsigned short*)w; w += (size_t)BATCH * KLEN * KDIM * 2;  // 16.8 MB
    unsigned short* qx   = (unsigned short*)w; w += (size_t)QROWS * KDIM * 2;         //  2.1 MB
    unsigned short* GT   = (unsigned short*)w; w += (size_t)GCOLS * 512 * 2;          //  2.6 MB
    unsigned short* qg   = (unsigned short*)w; w += (size_t)QROWS * GCOLS * 2;        // 10.5 MB
    float* aux    = (float*)w; w += 4096 * 4;
    float* vq2    = (float*)w; w += QROWS * 4;
    float* p_alpha = (float*)w; w += (size_t)BATCH * QLEN * KLEN * 4;                 // 16.8 MB
    float* mArr    = (float*)w; w += (size_t)BATCH * QLEN * KLEN * 4;                 // 16.8 MB
    float* rArr    = (float*)w;                                                       // 16.8 MB

    // 1) casts + G matrices + bias folds (1 launch)
    hipLaunchKernelGGL(prep_g, dim3(NKXB + NQXB + 93), dim3(256), 0, stream,
                       key_enc, query, Wk_m, Wk_c, Wq_m, Wq_c,
                       bq_m, bk_m, bq_c, kx, qx, GT, aux);

    // 2) qg = qx @ GT^T + wv  (+ vq2)
    hipLaunchKernelGGL(qg_kernel, dim3(328), dim3(256), 0, stream,
                       qx, GT, aux, qg, vq2);

    // 3) p_choose
    hipLaunchKernelGGL(pchoose_mfma, dim3(KLEN / 128, QLEN / 128, BATCH), dim3(256), 0, stream,
                       qg, kx, noise, rp, vq2, p_alpha);

    // 4) cumprod -> (m, r)  (standalone parallel kernel — R9 fusion regressed)
    hipLaunchKernelGGL(cumprod_mr, dim3(BATCH * QLEN), dim3(256), 0, stream,
                       p_alpha, mArr, rArr);

    // 5) FUSED: alpha recurrence (blocks 0..7, 2-steps-per-barrier) +
    //           e_chunk (blocks 8..519)
    hipLaunchKernelGGL(alpha_echunk, dim3(BATCH + 512), dim3(512), 0, stream,
                       mArr, rArr, p_alpha, qg, kx, out);

    // 6) beta (overwrites e_chunk rows in d_out)
    hipLaunchKernelGGL(beta_kernel, dim3(BATCH * NHEADS * QLEN), dim3(256), 0, stream,
                       out, p_alpha);
}